// Round 6
// baseline (73.180 us; speedup 1.0000x reference)
//
#include <hip/hip_runtime.h>
#include <stdint.h>

// Shapes fixed by setup_inputs(): B=2048, D=1024, H=1024.
#define BB 2048
#define DD 1024
#define HH 1024
#define KK 4096   // D + H + D + H : A' = [x | h_prev | x^2 | h_prev^2]
#define NN 2048   // 2*H : u-gate cols 0..1023, h-gate cols 1024..2047 (r-gate dead)

typedef __bf16 bf16x8 __attribute__((ext_vector_type(8)));
typedef float  f32x4  __attribute__((ext_vector_type(4)));
typedef unsigned short u16x8 __attribute__((ext_vector_type(8)));

__device__ __forceinline__ unsigned short f2bf(float f) {
  union { float f; uint32_t u; } v; v.f = f;
  uint32_t r = (v.u + 0x7FFFu + ((v.u >> 16) & 1u)) >> 16;  // RNE
  return (unsigned short)r;
}
__device__ __forceinline__ float bf2f(unsigned short u) {
  union { float f; uint32_t i; } v; v.i = ((uint32_t)u) << 16; return v.f;
}

__device__ __forceinline__ float softplus_f(float x) {
  return (x > 20.f) ? x : __logf(1.f + __expf(x));
}

// ---------- merged prep: blocks [0,2048) build W'T, blocks [2048,10240) build A' ---
// A' (2048 x 4096 bf16) = [x | h | x^2 | h^2]
// W'T (2048 x 4096 bf16), K-major, eps folded into sig rows.
__global__ __launch_bounds__(256) void prep_aw(const float* __restrict__ x,
                                               const float* __restrict__ h,
                                               unsigned short* __restrict__ A,
                                               const float* __restrict__ Wmu,
                                               const float* __restrict__ Wrho,
                                               const float* __restrict__ Umu,
                                               const float* __restrict__ Urho,
                                               const float* __restrict__ ueps,
                                               const float* __restrict__ heps,
                                               unsigned short* __restrict__ Wt) {
  __shared__ float tile[64][65];                // [k][n], 65-pad
  int bxx = blockIdx.x;
  if (bxx >= 2048) {
    // ---- prep_a part ----
    int T = (bxx - 2048) * 256 + threadIdx.x;
    int m  = T >> 10;
    int k4 = (T & 1023) << 2;
    int region = k4 >> 10;                      // 0:x 1:h 2:x^2 3:h^2
    int off = k4 & 1023;
    const float* src = (region & 1) ? h : x;
    float4 v = *(const float4*)(src + (size_t)m * 1024 + off);
    if (region >= 2) { v.x *= v.x; v.y *= v.y; v.z *= v.z; v.w *= v.w; }
    ushort4 o;
    o.x = f2bf(v.x); o.y = f2bf(v.y); o.z = f2bf(v.z); o.w = f2bf(v.w);
    *(ushort4*)(A + (size_t)m * KK + k4) = o;
    return;
  }
  // ---- prep_w part ----
  int bx = bxx;                                 // 32 n-tiles x 64 k-tiles
  int n0 = (bx & 31) * 64;
  int k0 = (bx >> 5) * 64;
  int t = threadIdx.x;

  const float* src; int rowbase; bool sig = (k0 >= 2048);
  if      (k0 < 1024) { src = Wmu;  rowbase = k0; }
  else if (k0 < 2048) { src = Umu;  rowbase = k0 - 1024; }
  else if (k0 < 3072) { src = Wrho; rowbase = k0 - 2048; }
  else                { src = Urho; rowbase = k0 - 3072; }

  int nn  = t & 63;                             // lanes sweep n: coalesced reads
  int kk0 = t >> 6;
  int n   = n0 + nn;
  float eps = 0.f;
  if (sig) eps = (n < 1024) ? ueps[n] : heps[n - 1024];
#pragma unroll
  for (int p = 0; p < 16; ++p) {
    int kk = p * 4 + kk0;
    float v = src[(size_t)(rowbase + kk) * 3072 + 1024 + n];
    if (sig) { float s = softplus_f(v); v = s * s * eps; }
    tile[kk][nn] = v;
  }
  __syncthreads();
  // write phase: each thread emits 2x 16B stores (8 bf16 along k)
#pragma unroll
  for (int p = 0; p < 2; ++p) {
    int idx = p * 256 + t;
    int nw  = idx >> 3;                         // 0..63
    int oc  = idx & 7;                          // k-octet
    u16x8 o8;
#pragma unroll
    for (int e = 0; e < 8; ++e) o8[e] = f2bf(tile[oc * 8 + e][nw]);
    *(u16x8*)&Wt[(size_t)(n0 + nw) * KK + k0 + oc * 8] = o8;
  }
}

// ================= GEMM v3: 128x256 tile, BK=32, 3-buf, 2 blocks/CU ==============
// G_z = A'[:, Kz] @ W'T[:, Kz]^T ; 8 waves (2Mx4N), per-wave 64x64 output.
// LDS per buffer: A 128x32 (8 KB) + B 256x32 (16 KB) = 24 KB; 3 buffers = 72 KB.
// Stage tile t+2 during t (3 gload16/thread); counted vmcnt(3); 2 barriers/kt.
// Chunk swizzle oct^(row&3) applied on global source + read side (both-sides rule).
__device__ __forceinline__ void gload16(const unsigned short* g, unsigned short* l) {
  __builtin_amdgcn_global_load_lds((const __attribute__((address_space(1))) void*)g,
                                   (__attribute__((address_space(3))) void*)l, 16, 0, 0);
}

#define BAR() { asm volatile("" ::: "memory"); __builtin_amdgcn_s_barrier(); \
                asm volatile("" ::: "memory"); }
#define WAITL() { asm volatile("s_waitcnt lgkmcnt(0)" ::: "memory"); \
                  __builtin_amdgcn_sched_barrier(0); }
#define VMC(N) { asm volatile("s_waitcnt vmcnt(" #N ")" ::: "memory"); }

template <int SPLITK>
__global__ __launch_bounds__(512, 4) void gemm256(const unsigned short* __restrict__ A,
                                                  const unsigned short* __restrict__ Bt,
                                                  unsigned short* __restrict__ Gb) {
  constexpr int KSTEPS = (KK / 32) / SPLITK;     // 32 k-tiles at SPLITK=4
  static_assert(KSTEPS >= 4, "");
  __shared__ __align__(16) unsigned short lds[36864];   // 72 KiB
  const int tid = threadIdx.x;
  const int bx  = blockIdx.x;
  const int tile = bx & 127;                     // 16(M) x 8(N) tiles
  const int kz   = bx >> 7;
  const int m0 = (tile >> 3) * 128;
  const int n0 = (tile & 7) * 256;
  const int kt0 = kz * KSTEPS;
  const int lane = tid & 63;
  const int wid  = tid >> 6;
  const int wm  = wid >> 2;        // 0..1 : 64-row band of the 128-row tile
  const int wn  = wid & 3;         // 0..3 : 64-col band of the 256-col tile
  const int lr  = lane & 15;
  const int lk  = lane >> 4;
  const int roct = lk ^ (lr & 3);  // read-side swizzled k-octet

  f32x4 acc[4][4];
#pragma unroll
  for (int i = 0; i < 4; ++i)
#pragma unroll
    for (int j = 0; j < 4; ++j) acc[i][j] = (f32x4)0.f;

  // stage tile tl into buffer sbuf (A: 512 chunks, B: 1024 chunks, 3/thread)
#define STAGE3(tl, sbuf) do { if ((tl) < KSTEPS) {                             \
    {                                                                          \
      int c = tid;  /* A chunk */                                              \
      int row = c >> 2, oc = (c & 3) ^ (row & 3);                              \
      gload16(A + (size_t)(m0 + row) * KK + (size_t)(kt0 + (tl)) * 32 + oc * 8,\
              &lds[(sbuf) * 12288 + c * 8]);                                   \
    }                                                                          \
    _Pragma("unroll") for (int j = 0; j < 2; ++j) {                            \
      int cb = j * 512 + tid;  /* B chunk */                                   \
      int row = cb >> 2, oc = (cb & 3) ^ (row & 3);                            \
      gload16(Bt + (size_t)(n0 + row) * KK + (size_t)(kt0 + (tl)) * 32 + oc * 8,\
              &lds[(sbuf) * 12288 + 4096 + cb * 8]);                           \
    } } } while (0)

  // -------- prologue: stage t0 -> buf0, t1 -> buf1; wait for t0 -------------
  STAGE3(0, 0);
  STAGE3(1, 1);
  VMC(3); BAR();

  int bufc = 0, sb = 2;
#pragma unroll 1
  for (int tc = 0; tc < KSTEPS; ++tc) {
    bf16x8 a[4], b[4];
#pragma unroll
    for (int f = 0; f < 4; ++f) {
      int row = wm * 64 + f * 16 + lr;
      a[f] = *(const bf16x8*)&lds[bufc * 12288 + row * 32 + roct * 8];
    }
#pragma unroll
    for (int f = 0; f < 4; ++f) {
      int row = wn * 64 + f * 16 + lr;
      b[f] = *(const bf16x8*)&lds[bufc * 12288 + 4096 + row * 32 + roct * 8];
    }
    STAGE3(tc + 2, sb);
    BAR(); WAITL();
    __builtin_amdgcn_s_setprio(1);
#pragma unroll
    for (int fi = 0; fi < 4; ++fi)
#pragma unroll
      for (int fj = 0; fj < 4; ++fj)
        acc[fi][fj] = __builtin_amdgcn_mfma_f32_16x16x32_bf16(a[fi], b[fj],
                                                              acc[fi][fj], 0, 0, 0);
    __builtin_amdgcn_s_setprio(0);
    if (tc + 3 <= KSTEPS) { VMC(3); } else { VMC(0); }
    BAR();
    bufc = (bufc == 2) ? 0 : bufc + 1;
    sb   = (sb   == 2) ? 0 : sb   + 1;
  }

  // ---- C repack: f32 acc -> bf16 via per-wave LDS scratch (swizzled), then
  //      16B-contiguous stores. All staging drained (final VMC(0)+BAR).
  unsigned short* wl = &lds[wid * 4096];        // 8 KiB per wave
#pragma unroll
  for (int fi = 0; fi < 4; ++fi)
#pragma unroll
    for (int fj = 0; fj < 4; ++fj) {
#pragma unroll
      for (int q = 0; q < 4; ++q) {
        int row = fi * 16 + lk * 4 + q;         // 0..63
        int col = fj * 16 + lr;                 // 0..63
        int oct = (col >> 3) ^ (row & 7);
        wl[row * 64 + oct * 8 + (col & 7)] = f2bf(acc[fi][fj][q]);
      }
    }
  unsigned short* Gz = Gb + (size_t)kz * BB * NN;
  {
    const int rl = lane >> 3;
    const int c8 = lane & 7;
#pragma unroll
    for (int i = 0; i < 8; ++i) {
      int r = i * 8 + rl;
      bf16x8 vv = *(const bf16x8*)&wl[r * 64 + ((c8 ^ (r & 7)) * 8)];
      *(bf16x8*)&Gz[(size_t)(m0 + wm * 64 + r) * NN + n0 + wn * 64 + c8 * 8] = vv;
    }
  }
#undef STAGE3
}

// ---------------- epilogue: split-K reduce (bf16 partials) + gates + mix ---------
template <int SPLITK>
__global__ __launch_bounds__(256) void epilogue(const unsigned short* __restrict__ Gb,
                                                const float* __restrict__ hprev,
                                                const float* __restrict__ bmu,
                                                const float* __restrict__ brho,
                                                const float* __restrict__ ueps,
                                                const float* __restrict__ heps,
                                                float* __restrict__ out) {
  int T = blockIdx.x * 256 + threadIdx.x;       // 262144 threads, 8 cols each
  int m  = T >> 7;
  int j8 = (T & 127) << 3;
  float gu[8] = {0.f,0.f,0.f,0.f,0.f,0.f,0.f,0.f};
  float gh[8] = {0.f,0.f,0.f,0.f,0.f,0.f,0.f,0.f};
#pragma unroll
  for (int z = 0; z < SPLITK; ++z) {
    const unsigned short* Gz = Gb + (size_t)z * BB * NN;
    u16x8 a = *(const u16x8*)(Gz + (size_t)m * NN + j8);
    u16x8 c = *(const u16x8*)(Gz + (size_t)m * NN + 1024 + j8);
#pragma unroll
    for (int e = 0; e < 8; ++e) { gu[e] += bf2f(a[e]); gh[e] += bf2f(c[e]); }
  }
  float hp[8], bu[8], ru[8], bh[8], rh[8], ue[8], he[8];
  *(float4*)&hp[0] = *(const float4*)(hprev + (size_t)m * 1024 + j8);
  *(float4*)&hp[4] = *(const float4*)(hprev + (size_t)m * 1024 + j8 + 4);
  *(float4*)&bu[0] = *(const float4*)(bmu + 1024 + j8);
  *(float4*)&bu[4] = *(const float4*)(bmu + 1024 + j8 + 4);
  *(float4*)&ru[0] = *(const float4*)(brho + 1024 + j8);
  *(float4*)&ru[4] = *(const float4*)(brho + 1024 + j8 + 4);
  *(float4*)&bh[0] = *(const float4*)(bmu + 2048 + j8);
  *(float4*)&bh[4] = *(const float4*)(bmu + 2048 + j8 + 4);
  *(float4*)&rh[0] = *(const float4*)(brho + 2048 + j8);
  *(float4*)&rh[4] = *(const float4*)(brho + 2048 + j8 + 4);
  *(float4*)&ue[0] = *(const float4*)(ueps + j8);
  *(float4*)&ue[4] = *(const float4*)(ueps + j8 + 4);
  *(float4*)&he[0] = *(const float4*)(heps + j8);
  *(float4*)&he[4] = *(const float4*)(heps + j8 + 4);
  float o[8];
#pragma unroll
  for (int c = 0; c < 8; ++c) {
    float zu = gu[c] + bu[c] + softplus_f(ru[c]) * ue[c];
    float zh = gh[c] + bh[c] + softplus_f(rh[c]) * he[c];
    float u  = 1.f / (1.f + __expf(-zu));
    float e2 = __expf(2.f * zh);
    float th = 1.f - 2.f / (e2 + 1.f);          // tanh, inf-safe
    o[c] = u * hp[c] + (1.f - u) * th;
  }
  *(float4*)(out + (size_t)m * 1024 + j8)     = *(const float4*)&o[0];
  *(float4*)(out + (size_t)m * 1024 + j8 + 4) = *(const float4*)&o[4];
}

extern "C" void kernel_launch(void* const* d_in, const int* in_sizes, int n_in,
                              void* d_out, int out_size, void* d_ws, size_t ws_size,
                              hipStream_t stream) {
  const float* x     = (const float*)d_in[0];
  const float* hprev = (const float*)d_in[1];
  const float* Wmu   = (const float*)d_in[2];
  const float* Wrho  = (const float*)d_in[3];
  const float* Umu   = (const float*)d_in[4];
  const float* Urho  = (const float*)d_in[5];
  const float* bmu   = (const float*)d_in[6];
  const float* brho  = (const float*)d_in[7];
  const float* ueps  = (const float*)d_in[9];   // d_in[8]=r_eps is dead code
  const float* heps  = (const float*)d_in[10];
  float* out = (float*)d_out;

  size_t aw = (size_t)BB * KK * 2;              // A' bf16, 16 MiB
  size_t ww = (size_t)NN * KK * 2;              // W'T bf16, 16 MiB
  size_t gw = (size_t)BB * NN * 2;              // bf16 partial, 8 MiB each
  unsigned short* Abf = (unsigned short*)d_ws;
  unsigned short* Wt  = (unsigned short*)((char*)d_ws + aw);
  unsigned short* Gb  = (unsigned short*)((char*)d_ws + aw + ww);

  int splitk = 1;
  if      (ws_size >= aw + ww + 4 * gw) splitk = 4;
  else if (ws_size >= aw + ww + 2 * gw) splitk = 2;

  prep_aw<<<10240, 256, 0, stream>>>(x, hprev, Abf, Wmu, Wrho, Umu, Urho,
                                     ueps, heps, Wt);
  if (splitk == 4) {
    gemm256<4><<<512, 512, 0, stream>>>(Abf, Wt, Gb);
    epilogue<4><<<1024, 256, 0, stream>>>(Gb, hprev, bmu, brho, ueps, heps, out);
  } else if (splitk == 2) {
    gemm256<2><<<256, 512, 0, stream>>>(Abf, Wt, Gb);
    epilogue<2><<<1024, 256, 0, stream>>>(Gb, hprev, bmu, brho, ueps, heps, out);
  } else {
    gemm256<1><<<128, 512, 0, stream>>>(Abf, Wt, Gb);
    epilogue<1><<<1024, 256, 0, stream>>>(Gb, hprev, bmu, brho, ueps, heps, out);
  }
}